// Round 5
// baseline (801.918 us; speedup 1.0000x reference)
//
#include <hip/hip_runtime.h>
#include <hip/hip_bf16.h>
#include <math.h>

#define TILE 128
#define BK 32

using short8  = __attribute__((ext_vector_type(8))) short;
using short4v = __attribute__((ext_vector_type(4))) short;
using f32x4   = __attribute__((ext_vector_type(4))) float;
typedef __hip_bfloat16 bf16;

constexpr int BB = 8, SEQ = 2048, C = 1024, H3 = 3072, DH = 512, MH = 2048;
constexpr int MR = BB * SEQ;  // 16384 token rows

enum {
  F_TRANSB = 1,   // B given as [N,K] row-major
  F_GELU   = 2,
  F_RES    = 4,
  F_OUTBF16= 8,
  F_BIAS   = 16,
  F_SCALE  = 32,
  F_RESF32 = 64
};

struct ZOffs { long long a[16]; long long b[16]; long long c[16]; };

__device__ __forceinline__ float bf2f(bf16 h) { return __bfloat162float(h); }

// async global->LDS, 16B per lane; LDS dest is wave-uniform base + lane*16
__device__ __forceinline__ void gload16(const void* g, void* l) {
  __builtin_amdgcn_global_load_lds(
      (const __attribute__((address_space(1))) unsigned int*)g,
      (__attribute__((address_space(3))) unsigned int*)l, 16, 0, 0);
}

// ---------------------------------------------------------------------------
// OLD 128x128 GEMM (kept only for the no-Vt fallback PV path, B=[K,N] layout)
// ---------------------------------------------------------------------------
template<int FLAGS>
__global__ __launch_bounds__(256) void gemm_k(
    const bf16* __restrict__ A,
    const bf16* __restrict__ B,
    void* __restrict__ Dst,
    const float* __restrict__ bias,
    const void* __restrict__ res,
    int K, int lda, int ldb, int ldc,
    float scale, ZOffs zo)
{
  __shared__ __align__(16) unsigned short As[TILE * BK];
  __shared__ __align__(16) unsigned short Bs[TILE * BK];
  const int tid = threadIdx.x;
  const int z = blockIdx.z;
  const int m0 = blockIdx.y * TILE, n0 = blockIdx.x * TILE;
  const bf16* Ab = A + zo.a[z];
  const bf16* Bb = B + zo.b[z];
  const long long coff = zo.c[z];
  const int wave = tid >> 6, lane = tid & 63;
  const int wm = (wave & 1) << 6, wn = (wave >> 1) << 6;
  const int lr = lane & 15, lq = lane >> 4;

  int srow[2], skb[2];
  #pragma unroll
  for (int i = 0; i < 2; i++) {
    int c = tid + (i << 8);
    srow[i] = c >> 2;
    skb[i]  = (c & 3) ^ ((srow[i] >> 1) & 3);
  }
  const bf16* Asrc[2]; const bf16* Bsrc[2] = {nullptr, nullptr};
  #pragma unroll
  for (int i = 0; i < 2; i++)
    Asrc[i] = Ab + (size_t)(m0 + srow[i]) * lda + skb[i] * 8;
  if (FLAGS & F_TRANSB) {
    #pragma unroll
    for (int i = 0; i < 2; i++)
      Bsrc[i] = Bb + (size_t)(n0 + srow[i]) * ldb + skb[i] * 8;
  }

  f32x4 acc[4][4] = {};
  const int swl = (lr >> 1) & 3;

  for (int k0 = 0; k0 < K; k0 += BK) {
    #pragma unroll
    for (int i = 0; i < 2; i++)
      gload16(Asrc[i] + k0, &As[(tid + (i << 8)) * 8]);
    if (FLAGS & F_TRANSB) {
      #pragma unroll
      for (int i = 0; i < 2; i++)
        gload16(Bsrc[i] + k0, &Bs[(tid + (i << 8)) * 8]);
    } else {
      #pragma unroll
      for (int i = 0; i < 2; i++) {
        int c = tid + (i << 8);
        int kk = c >> 4, nn = (c & 15) << 3;
        unsigned short tmp[8];
        *(uint4*)tmp = *(const uint4*)(Bb + (size_t)(k0 + kk) * ldb + n0 + nn);
        #pragma unroll
        for (int j = 0; j < 8; j++) {
          int n = nn + j;
          Bs[n * BK + (((kk >> 3) ^ ((n >> 1) & 3)) << 3) + (kk & 7)] = tmp[j];
        }
      }
    }
    __syncthreads();
    short8 af[4], bfr[4];
    #pragma unroll
    for (int mi = 0; mi < 4; mi++)
      af[mi] = *(const short8*)&As[(wm + mi * 16 + lr) * BK + ((lq ^ swl) << 3)];
    #pragma unroll
    for (int ni = 0; ni < 4; ni++)
      bfr[ni] = *(const short8*)&Bs[(wn + ni * 16 + lr) * BK + ((lq ^ swl) << 3)];
    #pragma unroll
    for (int mi = 0; mi < 4; mi++)
      #pragma unroll
      for (int ni = 0; ni < 4; ni++)
        acc[mi][ni] = __builtin_amdgcn_mfma_f32_16x16x32_bf16(
            af[mi], bfr[ni], acc[mi][ni], 0, 0, 0);
    __syncthreads();
  }

  #pragma unroll
  for (int mi = 0; mi < 4; mi++) {
    #pragma unroll
    for (int ni = 0; ni < 4; ni++) {
      int col = n0 + wn + ni * 16 + lr;
      float bv = (FLAGS & F_BIAS) ? bias[col] : 0.0f;
      #pragma unroll
      for (int r = 0; r < 4; r++) {
        int row = m0 + wm + mi * 16 + lq * 4 + r;
        float v = acc[mi][ni][r];
        if (FLAGS & F_SCALE) v *= scale;
        v += bv;
        if (FLAGS & F_GELU) v = 0.5f * v * (1.0f + erff(v * 0.70710678118654752f));
        if (FLAGS & F_RES) {
          size_t ridx = (size_t)row * ldc + col;
          v += (FLAGS & F_RESF32) ? ((const float*)res)[ridx]
                                  : bf2f(((const bf16*)res)[ridx]);
        }
        size_t idx = (size_t)coff + (size_t)row * ldc + col;
        if (FLAGS & F_OUTBF16) ((bf16*)Dst)[idx] = __float2bfloat16(v);
        else                   ((float*)Dst)[idx] = v;
      }
    }
  }
}

// ---------------------------------------------------------------------------
// 256x256 GEMM, BK=32, 512 threads = 8 waves (2M x 4N), per-wave 128x64 out.
// BARRIER-MINIMAL schedule: ONE counted vmcnt + ONE s_barrier per K-tile.
// 3-buffer LDS FIFO (3 x 32 KB = 96 KB), prefetch depth 2: tile t lives in
// buf[t%3]; staging for tile t+2 (4 gloads/thread) is issued during tile t
// into buf[(t+2)%3]. Tile body is straight-line (12 ds_read_b128 + 32 MFMA),
// compiler-scheduled, NO intra-tile barriers -> waves de-phase within the
// tile so one wave's LDS latency hides under another's MFMAs (m114 overlap).
//
// Liveness proof for staging into buf[(t+2)%3] == buf[(t-1)%3]:
//   - readers of tile t-1 retired their ds_reads before issuing their last
//     MFMA (register dependence), hence before arriving at tile-top-t
//     barrier; staging gloads are issued after that barrier (asm memory
//     fences pin the order), and their LDS writes land later still. No race.
//   - wave skew across the barrier is impossible (barrier blocks).
// vmcnt FIFO: prologue stages tiles 0,1 (4+4). At top of tile t the newest
// 4 outstanding are stage(t+1); vmcnt(4) retires stage(t) -> buffer ready.
// Last tile waits vmcnt(0). Steady-state never drains the queue.
// T1 XCD swizzle, T2 XOR slot swizzle (conflict-free), T5 setprio.
// Requires F_TRANSB, M,N % 256 == 0, K % 32 == 0.
// ---------------------------------------------------------------------------
template<int FLAGS>
__global__ __launch_bounds__(512, 2) void gemm256_k(
    const bf16* __restrict__ A,
    const bf16* __restrict__ B,
    void* __restrict__ Dst,
    const float* __restrict__ bias,
    const void* __restrict__ res,
    int K, int lda, int ldb, int ldc,
    float scale, ZOffs zo)
{
  static_assert(FLAGS & F_TRANSB, "gemm256_k requires B^T layout");
  extern __shared__ __align__(16) unsigned short smem[];  // 3 x [A 8K | B 8K] ushorts

  const int tid = threadIdx.x;
  const int z = blockIdx.z;

  // T1: bijective XCD swizzle over (bx,by); all grids have nwg % 8 == 0.
  const int gx = gridDim.x;
  const int nwg = gx * gridDim.y;
  const int wg = blockIdx.y * gx + blockIdx.x;
  const int cpx = nwg >> 3;
  const int swz = (wg & 7) * cpx + (wg >> 3);
  const int m0 = (swz / gx) * 256, n0 = (swz % gx) * 256;

  const bf16* Ab = A + zo.a[z];
  const bf16* Bb = B + zo.b[z];
  const long long coff = zo.c[z];
  const int wave = tid >> 6, lane = tid & 63;
  const int wm = wave >> 2, wn = wave & 3;         // 2 x 4 wave grid
  const int lr = lane & 15, lq = lane >> 4;
  const int swl = (lr >> 1) & 3;
  const int kcol = (lq ^ swl) << 3;                // swizzled k-slot (ushort idx)

  // staging: chunk c = tid + i*512, c in [0,1024): row=c>>2, dest slot=c&3,
  // source k-slot = (c&3) ^ ((row>>1)&3)  (XOR swizzle via pre-swizzled src)
  const int c0 = tid, c1 = tid + 512;
  const int row0 = c0 >> 2, sl0 = (c0 & 3) ^ ((row0 >> 1) & 3);
  const int row1 = c1 >> 2, sl1 = (c1 & 3) ^ ((row1 >> 1) & 3);
  const bf16* sA0 = Ab + (size_t)(m0 + row0) * lda + sl0 * 8;
  const bf16* sA1 = Ab + (size_t)(m0 + row1) * lda + sl1 * 8;
  const bf16* sB0 = Bb + (size_t)(n0 + row0) * ldb + sl0 * 8;
  const bf16* sB1 = Bb + (size_t)(n0 + row1) * ldb + sl1 * 8;
  const int dst0 = c0 * 8, dst1 = c1 * 8;          // LDS dest (ushort idx)

  const int nt = K >> 5;                           // K-tiles of 32

#define STAGE(ks_, D_)                                                         \
  do {                                                                         \
    gload16(sA0 + (ks_), (D_) + dst0);                                         \
    gload16(sA1 + (ks_), (D_) + dst1);                                         \
    gload16(sB0 + (ks_), (D_) + 8192 + dst0);                                  \
    gload16(sB1 + (ks_), (D_) + 8192 + dst1);                                  \
  } while (0)

  // prologue: stage tile 0 -> buf0, tile 1 -> buf1 (FIFO order)
  STAGE(0, smem);
  if (nt > 1) STAGE(32, smem + 16384);

  f32x4 acc[8][4] = {};
  short8 af[4], bf4[4];
  int bc = 0, bs = 2;                              // current / stage buffer idx

  for (int t = 0; t < nt; ++t) {
    if (t == nt - 1) asm volatile("s_waitcnt vmcnt(0)" ::: "memory");
    else             asm volatile("s_waitcnt vmcnt(4)" ::: "memory");
    __builtin_amdgcn_s_barrier();
    asm volatile("" ::: "memory");                 // no mem op crosses barrier

    // stage tile t+2 into buf bs (cold: its readers retired pre-barrier)
    if (t + 2 < nt) STAGE((t + 2) * 32, smem + bs * 16384);

    const unsigned short* At = smem + bc * 16384;
    const unsigned short* Bt = At + 8192;

    #pragma unroll
    for (int n_ = 0; n_ < 4; ++n_)
      bf4[n_] = *(const short8*)&Bt[(wn * 64 + n_ * 16 + lr) * 32 + kcol];
    #pragma unroll
    for (int mh = 0; mh < 2; ++mh) {
      #pragma unroll
      for (int m_ = 0; m_ < 4; ++m_)
        af[m_] = *(const short8*)&At[(wm * 128 + mh * 64 + m_ * 16 + lr) * 32 + kcol];
      __builtin_amdgcn_s_setprio(1);
      #pragma unroll
      for (int m_ = 0; m_ < 4; ++m_)
        #pragma unroll
        for (int n_ = 0; n_ < 4; ++n_)
          acc[mh * 4 + m_][n_] = __builtin_amdgcn_mfma_f32_16x16x32_bf16(
              af[m_], bf4[n_], acc[mh * 4 + m_][n_], 0, 0, 0);
      __builtin_amdgcn_s_setprio(0);
    }
    bc = bc == 2 ? 0 : bc + 1;
    bs = bs == 2 ? 0 : bs + 1;
  }

#undef STAGE

  // epilogue: C/D layout col=lane&15, row=quad*4+reg
  const int colBase = n0 + wn * 64 + lr;
  float bv[4];
  #pragma unroll
  for (int n = 0; n < 4; ++n)
    bv[n] = (FLAGS & F_BIAS) ? bias[colBase + n * 16] : 0.0f;
  #pragma unroll
  for (int m = 0; m < 8; ++m) {
    #pragma unroll
    for (int n = 0; n < 4; ++n) {
      const int col = colBase + n * 16;
      #pragma unroll
      for (int r = 0; r < 4; ++r) {
        const int row = m0 + wm * 128 + m * 16 + lq * 4 + r;
        float v = acc[m][n][r];
        if (FLAGS & F_SCALE) v *= scale;
        v += bv[n];
        if (FLAGS & F_GELU) v = 0.5f * v * (1.0f + erff(v * 0.70710678118654752f));
        if (FLAGS & F_RES) {
          size_t ridx = (size_t)row * ldc + col;
          v += (FLAGS & F_RESF32) ? ((const float*)res)[ridx]
                                  : bf2f(((const bf16*)res)[ridx]);
        }
        size_t idx = (size_t)coff + (size_t)row * ldc + col;
        if (FLAGS & F_OUTBF16) ((bf16*)Dst)[idx] = __float2bfloat16(v);
        else                   ((float*)Dst)[idx] = v;
      }
    }
  }
}

// ---------- weight transpose+convert: src fp32 [K,N] -> dst bf16 [N,K] ----------
__global__ __launch_bounds__(256) void tconv_kernel(
    const float* __restrict__ src, bf16* __restrict__ dst, int K, int N)
{
  __shared__ float t[32][33];
  int n0 = blockIdx.x * 32, k0 = blockIdx.y * 32;
  int c = threadIdx.x & 31, r = threadIdx.x >> 5;
  #pragma unroll
  for (int i = 0; i < 4; i++)
    t[r + i * 8][c] = src[(size_t)(k0 + r + i * 8) * N + n0 + c];
  __syncthreads();
  #pragma unroll
  for (int i = 0; i < 4; i++)
    dst[(size_t)(n0 + r + i * 8) * K + k0 + c] = __float2bfloat16(t[c][r + i * 8]);
}

// ---------- V transpose: qkv V-slice [n][d] -> Vt[bh][d][n] (bf16) ----------
__global__ __launch_bounds__(256) void vtrans_kernel(
    const bf16* __restrict__ qkv, bf16* __restrict__ vt)
{
  __shared__ unsigned short t[32][33];
  int bh = blockIdx.z, b = bh >> 1, h = bh & 1;
  int n0 = blockIdx.x * 32, d0 = blockIdx.y * 32;
  int c = threadIdx.x & 31, r = threadIdx.x >> 5;
  const bf16* src = qkv + (size_t)b * SEQ * H3 + 2 * C + (size_t)h * DH;
  #pragma unroll
  for (int i = 0; i < 4; i++)
    t[r + i * 8][c] = *(const unsigned short*)&src[(size_t)(n0 + r + i * 8) * H3 + d0 + c];
  __syncthreads();
  bf16* dst = vt + ((size_t)bh * DH + d0) * SEQ + n0;
  #pragma unroll
  for (int i = 0; i < 4; i++)
    *(unsigned short*)&dst[(size_t)(r + i * 8) * SEQ + c] = t[c][r + i * 8];
}

// ---------- vectorized loads for LN ----------
__device__ __forceinline__ void ld4(const float* p, float v[4]) {
  const float4 t = *(const float4*)p;
  v[0] = t.x; v[1] = t.y; v[2] = t.z; v[3] = t.w;
}
__device__ __forceinline__ void ld4(const bf16* p, float v[4]) {
  short4v t = *(const short4v*)p;
  #pragma unroll
  for (int i = 0; i < 4; ++i) v[i] = bf2f(((const bf16*)&t)[i]);
}

// ---------- LayerNorm over C=1024, one block per row (vectorized) ----------
template<typename T>
__global__ __launch_bounds__(256) void ln_kernel(
    const T* __restrict__ x,
    const float* __restrict__ w,
    const float* __restrict__ b,
    bf16* __restrict__ out)
{
  __shared__ float sm[4], sm2[4];
  int row = blockIdx.x, tid = threadIdx.x;
  float v[4];
  ld4(x + (size_t)row * 1024 + tid * 4, v);
  float s  = v[0] + v[1] + v[2] + v[3];
  float sq = v[0]*v[0] + v[1]*v[1] + v[2]*v[2] + v[3]*v[3];
  #pragma unroll
  for (int o = 32; o > 0; o >>= 1) {
    s  += __shfl_down(s, o, 64);
    sq += __shfl_down(sq, o, 64);
  }
  int wvi = tid >> 6, lnn = tid & 63;
  if (lnn == 0) { sm[wvi] = s; sm2[wvi] = sq; }
  __syncthreads();
  s  = sm[0] + sm[1] + sm[2] + sm[3];
  sq = sm2[0] + sm2[1] + sm2[2] + sm2[3];
  float mean = s * (1.0f / 1024.0f);
  float var  = sq * (1.0f / 1024.0f) - mean * mean;
  float rs = rsqrtf(var + 1e-5f);
  float wv4[4], bv4[4];
  ld4(w + tid * 4, wv4);
  ld4(b + tid * 4, bv4);
  short4v o4;
  #pragma unroll
  for (int i = 0; i < 4; ++i)
    ((bf16*)&o4)[i] = __float2bfloat16((v[i] - mean) * rs * wv4[i] + bv4[i]);
  *(short4v*)&out[(size_t)row * 1024 + tid * 4] = o4;
}

// ---------- row softmax over 2048, IN-PLACE (bf16, short8 vectorized) ----------
__global__ __launch_bounds__(256) void softmax_kernel(
    bf16* __restrict__ sc)
{
  __shared__ float sm[4];
  int tid = threadIdx.x;
  size_t base = ((size_t)blockIdx.y * 2048 + blockIdx.x) * 2048 + (size_t)tid * 8;
  short8 sv = *(const short8*)&sc[base];
  float v[8], m = -1e30f;
  #pragma unroll
  for (int i = 0; i < 8; i++) { v[i] = bf2f(((const bf16*)&sv)[i]); m = fmaxf(m, v[i]); }
  #pragma unroll
  for (int o = 32; o > 0; o >>= 1) m = fmaxf(m, __shfl_down(m, o, 64));
  int wvi = tid >> 6, lnn = tid & 63;
  if (lnn == 0) sm[wvi] = m;
  __syncthreads();
  m = fmaxf(fmaxf(sm[0], sm[1]), fmaxf(sm[2], sm[3]));
  __syncthreads();
  float s = 0.f;
  #pragma unroll
  for (int i = 0; i < 8; i++) { v[i] = __expf(v[i] - m); s += v[i]; }
  #pragma unroll
  for (int o = 32; o > 0; o >>= 1) s += __shfl_down(s, o, 64);
  if (lnn == 0) sm[wvi] = s;
  __syncthreads();
  s = sm[0] + sm[1] + sm[2] + sm[3];
  float inv = 1.0f / s;
  short8 ov;
  #pragma unroll
  for (int i = 0; i < 8; i++)
    ((bf16*)&ov)[i] = __float2bfloat16(v[i] * inv);
  *(short8*)&sc[base] = ov;
}

// ---------------- host ----------------
#define G256(FL, grid_, A_, B_, D_, bias_, res_, K_, lda_, ldb_, ldc_, sc_, zo_)      \
  do {                                                                                \
    (void)hipFuncSetAttribute(reinterpret_cast<const void*>(&gemm256_k<(FL)>),        \
                              hipFuncAttributeMaxDynamicSharedMemorySize, 98304);     \
    hipLaunchKernelGGL((gemm256_k<(FL)>), grid_, dim3(512), 98304, stream,            \
                       A_, B_, D_, bias_, res_, K_, lda_, ldb_, ldc_, sc_, zo_);      \
  } while (0)

extern "C" void kernel_launch(void* const* d_in, const int* in_sizes, int n_in,
                              void* d_out, int out_size, void* d_ws, size_t ws_size,
                              hipStream_t stream) {
  const float* x      = (const float*)d_in[0];
  const float* ln1_w  = (const float*)d_in[1];
  const float* ln1_b  = (const float*)d_in[2];
  const float* qkv_w  = (const float*)d_in[3];
  const float* qkv_b  = (const float*)d_in[4];
  const float* proj_w = (const float*)d_in[5];
  const float* proj_b = (const float*)d_in[6];
  const float* ln2_w  = (const float*)d_in[7];
  const float* ln2_b  = (const float*)d_in[8];
  const float* mlp_w1 = (const float*)d_in[9];
  const float* mlp_b1 = (const float*)d_in[10];
  const float* mlp_w2 = (const float*)d_in[11];
  const float* mlp_b2 = (const float*)d_in[12];
  float* out = (float*)d_out;

  char* ws = (char*)d_ws;
  const size_t MB = 1ull << 20;
  bf16* qkvT  = (bf16*)ws;
  bf16* projT = qkvT + 3 * 1024 * 1024;
  bf16* w1T   = qkvT + 4 * 1024 * 1024;
  bf16* w2T   = qkvT + 6 * 1024 * 1024;
  bf16* xn    = (bf16*)(ws + 16 * MB);
  bf16* qkvb  = (bf16*)(ws + 48 * MB);
  bf16* h1    = qkvb;
  bf16* Vt    = (bf16*)(ws + 144 * MB);

  int CH; bool useVt, x1f32;
  if      (ws_size >= 304 * MB) { CH = 16; useVt = true;  x1f32 = true;  }
  else if (ws_size >= 240 * MB) { CH = 8;  useVt = true;  x1f32 = true;  }
  else if (ws_size >= 208 * MB) { CH = 4;  useVt = true;  x1f32 = false; }
  else                          { CH = 4;  useVt = false; x1f32 = false; }
  char* R = ws + (useVt ? 176 * MB : 144 * MB);
  bf16*  scores = (bf16*)R;
  float* x1f    = (float*)R;   // overlays scores after attention
  bf16*  x1h    = (bf16*)R;

  ZOffs z0 = {};
  const float scale = 0.04419417382415922f;  // 1/sqrt(512)
  dim3 blk(256);

  // 0. weight transpose+convert
  hipLaunchKernelGGL(tconv_kernel, dim3(H3 / 32, C / 32), blk, 0, stream, qkv_w, qkvT, C, H3);
  hipLaunchKernelGGL(tconv_kernel, dim3(C / 32, C / 32), blk, 0, stream, proj_w, projT, C, C);
  hipLaunchKernelGGL(tconv_kernel, dim3(MH / 32, C / 32), blk, 0, stream, mlp_w1, w1T, C, MH);
  hipLaunchKernelGGL(tconv_kernel, dim3(C / 32, MH / 32), blk, 0, stream, mlp_w2, w2T, MH, C);

  // 1. LN1
  hipLaunchKernelGGL((ln_kernel<float>), dim3(MR), blk, 0, stream, x, ln1_w, ln1_b, xn);

  // 2. QKV = xn @ qkv_w + b -> bf16 [16384,3072]
  G256(F_TRANSB | F_BIAS | F_OUTBF16, dim3(H3 / 256, MR / 256, 1),
       xn, qkvT, (void*)qkvb, qkv_b, nullptr, C, C, C, H3, 1.0f, z0);

  // 2b. Vt
  if (useVt)
    hipLaunchKernelGGL(vtrans_kernel, dim3(SEQ / 32, DH / 32, 16), blk, 0, stream, qkvb, Vt);

  // 3. attention in chunks of CH (b,h) pairs
  for (int ch = 0; ch < 16 / CH; ch++) {
    ZOffs zq = {}, zp = {};
    for (int zz = 0; zz < CH; zz++) {
      int bh = ch * CH + zz, b = bh >> 1, hh = bh & 1;
      zq.a[zz] = (long long)b * SEQ * H3 + (long long)hh * DH;          // Q
      zq.b[zz] = (long long)b * SEQ * H3 + C + (long long)hh * DH;      // K
      zq.c[zz] = (long long)zz * SEQ * SEQ;                             // scores
      zp.a[zz] = (long long)zz * SEQ * SEQ;                             // probs
      zp.b[zz] = useVt ? (long long)bh * DH * SEQ                       // Vt slice
                       : (long long)b * SEQ * H3 + 2 * C + (long long)hh * DH;
      zp.c[zz] = (long long)b * SEQ * C + (long long)hh * DH;           // attn_out
    }
    G256(F_TRANSB | F_SCALE | F_OUTBF16, dim3(SEQ / 256, SEQ / 256, CH),
         qkvb, qkvb, (void*)scores, nullptr, nullptr, DH, H3, H3, SEQ, scale, zq);
    hipLaunchKernelGGL(softmax_kernel, dim3(SEQ, CH), blk, 0, stream, scores);
    if (useVt)
      G256(F_TRANSB | F_OUTBF16, dim3(DH / 256, SEQ / 256, CH),
           scores, Vt, (void*)xn, nullptr, nullptr, SEQ, SEQ, SEQ, C, 1.0f, zp);
    else
      hipLaunchKernelGGL((gemm_k<F_OUTBF16>),
                         dim3(DH / TILE, SEQ / TILE, CH), blk, 0, stream,
                         scores, qkvb, (void*)xn, nullptr, nullptr, SEQ, SEQ, H3, C, 1.0f, zp);
  }

  // 4. x1 = attn_out @ proj_w + b + x ; LN2 -> xn2
  if (x1f32) {
    G256(F_TRANSB | F_BIAS | F_RES | F_RESF32, dim3(C / 256, MR / 256, 1),
         xn, projT, (void*)x1f, proj_b, (const void*)x, C, C, C, C, 1.0f, z0);
    hipLaunchKernelGGL((ln_kernel<float>), dim3(MR), blk, 0, stream, x1f, ln2_w, ln2_b, xn);
  } else {
    G256(F_TRANSB | F_BIAS | F_RES | F_RESF32 | F_OUTBF16, dim3(C / 256, MR / 256, 1),
         xn, projT, (void*)x1h, proj_b, (const void*)x, C, C, C, C, 1.0f, z0);
    hipLaunchKernelGGL((ln_kernel<bf16>), dim3(MR), blk, 0, stream, x1h, ln2_w, ln2_b, xn);
  }

  // 5. h1 = gelu(xn2 @ w1 + b1) -> bf16 [16384,2048]
  G256(F_TRANSB | F_BIAS | F_GELU | F_OUTBF16, dim3(MH / 256, MR / 256, 1),
       xn, w1T, (void*)h1, mlp_b1, nullptr, C, C, C, MH, 1.0f, z0);

  // 6. out = x1 + h1 @ w2 + b2 -> fp32 d_out
  if (x1f32) {
    G256(F_TRANSB | F_BIAS | F_RES | F_RESF32, dim3(C / 256, MR / 256, 1),
         h1, w2T, (void*)out, mlp_b2, (const void*)x1f, MH, MH, MH, C, 1.0f, z0);
  } else {
    G256(F_TRANSB | F_BIAS | F_RES, dim3(C / 256, MR / 256, 1),
         h1, w2T, (void*)out, mlp_b2, (const void*)x1h, MH, MH, MH, C, 1.0f, z0);
  }
}

// Round 6
// 782.199 us; speedup vs baseline: 1.0252x; 1.0252x over previous
//
#include <hip/hip_runtime.h>
#include <hip/hip_bf16.h>
#include <math.h>

#define TILE 128
#define BK 32

using short8  = __attribute__((ext_vector_type(8))) short;
using short4v = __attribute__((ext_vector_type(4))) short;
using f32x4   = __attribute__((ext_vector_type(4))) float;
typedef __hip_bfloat16 bf16;

constexpr int BB = 8, SEQ = 2048, C = 1024, H3 = 3072, DH = 512, MH = 2048;
constexpr int MR = BB * SEQ;  // 16384 token rows

enum {
  F_TRANSB = 1,   // B given as [N,K] row-major
  F_GELU   = 2,
  F_RES    = 4,
  F_OUTBF16= 8,
  F_BIAS   = 16,
  F_SCALE  = 32,
  F_RESF32 = 64
};

struct ZOffs { long long a[16]; long long b[16]; long long c[16]; };

__device__ __forceinline__ float bf2f(bf16 h) { return __bfloat162float(h); }

// async global->LDS, 16B per lane; LDS dest is wave-uniform base + lane*16
__device__ __forceinline__ void gload16(const void* g, void* l) {
  __builtin_amdgcn_global_load_lds(
      (const __attribute__((address_space(1))) unsigned int*)g,
      (__attribute__((address_space(3))) unsigned int*)l, 16, 0, 0);
}

// fast GELU (tanh form): v * e/(e+1), e = exp(2*0.79788456*(v + 0.044715 v^3))
// max abs deviation from exact-erf GELU ~1e-3, below h1's bf16 quantization.
__device__ __forceinline__ float gelu_fast(float v) {
  float u2 = v * (1.5957691216057308f + 0.0713548162726009f * v * v);
  float e  = __expf(u2);
  return v - v * (1.0f / (e + 1.0f));
}

// ---------------------------------------------------------------------------
// OLD 128x128 GEMM (kept only for the no-Vt fallback PV path, B=[K,N] layout)
// ---------------------------------------------------------------------------
template<int FLAGS>
__global__ __launch_bounds__(256) void gemm_k(
    const bf16* __restrict__ A,
    const bf16* __restrict__ B,
    void* __restrict__ Dst,
    const float* __restrict__ bias,
    const void* __restrict__ res,
    int K, int lda, int ldb, int ldc,
    float scale, ZOffs zo)
{
  __shared__ __align__(16) unsigned short As[TILE * BK];
  __shared__ __align__(16) unsigned short Bs[TILE * BK];
  const int tid = threadIdx.x;
  const int z = blockIdx.z;
  const int m0 = blockIdx.y * TILE, n0 = blockIdx.x * TILE;
  const bf16* Ab = A + zo.a[z];
  const bf16* Bb = B + zo.b[z];
  const long long coff = zo.c[z];
  const int wave = tid >> 6, lane = tid & 63;
  const int wm = (wave & 1) << 6, wn = (wave >> 1) << 6;
  const int lr = lane & 15, lq = lane >> 4;

  int srow[2], skb[2];
  #pragma unroll
  for (int i = 0; i < 2; i++) {
    int c = tid + (i << 8);
    srow[i] = c >> 2;
    skb[i]  = (c & 3) ^ ((srow[i] >> 1) & 3);
  }
  const bf16* Asrc[2]; const bf16* Bsrc[2] = {nullptr, nullptr};
  #pragma unroll
  for (int i = 0; i < 2; i++)
    Asrc[i] = Ab + (size_t)(m0 + srow[i]) * lda + skb[i] * 8;
  if (FLAGS & F_TRANSB) {
    #pragma unroll
    for (int i = 0; i < 2; i++)
      Bsrc[i] = Bb + (size_t)(n0 + srow[i]) * ldb + skb[i] * 8;
  }

  f32x4 acc[4][4] = {};
  const int swl = (lr >> 1) & 3;

  for (int k0 = 0; k0 < K; k0 += BK) {
    #pragma unroll
    for (int i = 0; i < 2; i++)
      gload16(Asrc[i] + k0, &As[(tid + (i << 8)) * 8]);
    if (FLAGS & F_TRANSB) {
      #pragma unroll
      for (int i = 0; i < 2; i++)
        gload16(Bsrc[i] + k0, &Bs[(tid + (i << 8)) * 8]);
    } else {
      #pragma unroll
      for (int i = 0; i < 2; i++) {
        int c = tid + (i << 8);
        int kk = c >> 4, nn = (c & 15) << 3;
        unsigned short tmp[8];
        *(uint4*)tmp = *(const uint4*)(Bb + (size_t)(k0 + kk) * ldb + n0 + nn);
        #pragma unroll
        for (int j = 0; j < 8; j++) {
          int n = nn + j;
          Bs[n * BK + (((kk >> 3) ^ ((n >> 1) & 3)) << 3) + (kk & 7)] = tmp[j];
        }
      }
    }
    __syncthreads();
    short8 af[4], bfr[4];
    #pragma unroll
    for (int mi = 0; mi < 4; mi++)
      af[mi] = *(const short8*)&As[(wm + mi * 16 + lr) * BK + ((lq ^ swl) << 3)];
    #pragma unroll
    for (int ni = 0; ni < 4; ni++)
      bfr[ni] = *(const short8*)&Bs[(wn + ni * 16 + lr) * BK + ((lq ^ swl) << 3)];
    #pragma unroll
    for (int mi = 0; mi < 4; mi++)
      #pragma unroll
      for (int ni = 0; ni < 4; ni++)
        acc[mi][ni] = __builtin_amdgcn_mfma_f32_16x16x32_bf16(
            af[mi], bfr[ni], acc[mi][ni], 0, 0, 0);
    __syncthreads();
  }

  #pragma unroll
  for (int mi = 0; mi < 4; mi++) {
    #pragma unroll
    for (int ni = 0; ni < 4; ni++) {
      int col = n0 + wn + ni * 16 + lr;
      float bv = (FLAGS & F_BIAS) ? bias[col] : 0.0f;
      #pragma unroll
      for (int r = 0; r < 4; r++) {
        int row = m0 + wm + mi * 16 + lq * 4 + r;
        float v = acc[mi][ni][r];
        if (FLAGS & F_SCALE) v *= scale;
        v += bv;
        if (FLAGS & F_GELU) v = gelu_fast(v);
        if (FLAGS & F_RES) {
          size_t ridx = (size_t)row * ldc + col;
          v += (FLAGS & F_RESF32) ? ((const float*)res)[ridx]
                                  : bf2f(((const bf16*)res)[ridx]);
        }
        size_t idx = (size_t)coff + (size_t)row * ldc + col;
        if (FLAGS & F_OUTBF16) ((bf16*)Dst)[idx] = __float2bfloat16(v);
        else                   ((float*)Dst)[idx] = v;
      }
    }
  }
}

// ---------------------------------------------------------------------------
// 256x256 GEMM, BK=32, 512 threads = 8 waves (2M x 4N), per-wave 128x64 out.
// FRAGMENT PING-PONG schedule: LDS port <-> matrix pipe overlap INSIDE each
// wave. Per K-tile per CU the MFMA floor is ~1242 cyc and the LDS-read
// traffic is ~1150 cyc (A read 4x, B read 2x by the wave grid); previous
// schedules serialized them (all waves read, then all waves MFMA -> ~2750
// cyc/tile, MfmaUtil 38%). Here tile t's fragments are ALREADY in registers
// when the tile starts; during tile t we read tile t+1's fragments:
//   [vmcnt(4) barrier] issue stage(t+3); read af1(t) (pinned first by
//   sched_barrier); MFMA mh0 (regs ready, starts immediately); read
//   bf(t+1)+af0(t+1) from buf[t+1] under the MFMA shadow; MFMA mh1.
// 4 LDS buffers (4 x 32 KB = 128 KB), prefetch depth 3.
// vmcnt FIFO (per wave): prologue stages t0,t1,t2 (12 loads), vmcnt(8)
// retires stage(0) -> prologue frag reads. Top of tile t: outstanding =
// stage(t+1), stage(t+2) = 8; vmcnt(4) retires stage(t+1) (its buffer is
// read THIS tile). Body issues stage(t+3). Last tiles degenerate to no-ops.
// Staging buf[(t+3)&3] = buf[(t-1)&3] during t: its last reads (af1(t-1))
// retired before mh1(t-1)'s MFMAs (register dep), hence before the top-of-t
// barrier; stage issues after that barrier (memory-clobber fenced). No race.
// T1 XCD swizzle, T2 XOR slot swizzle (bank-conflict-free), T5 setprio.
// Requires F_TRANSB, M,N % 256 == 0, K % 64 == 0 (nt even).
// ---------------------------------------------------------------------------
template<int FLAGS>
__global__ __launch_bounds__(512, 2) void gemm256_k(
    const bf16* __restrict__ A,
    const bf16* __restrict__ B,
    void* __restrict__ Dst,
    const float* __restrict__ bias,
    const void* __restrict__ res,
    int K, int lda, int ldb, int ldc,
    float scale, ZOffs zo)
{
  static_assert(FLAGS & F_TRANSB, "gemm256_k requires B^T layout");
  extern __shared__ __align__(16) unsigned short smem[];  // 4 x [A 16K | B 16K]

  const int tid = threadIdx.x;
  const int z = blockIdx.z;

  // T1: bijective XCD swizzle over (bx,by); all grids have nwg % 8 == 0.
  const int gx = gridDim.x;
  const int nwg = gx * gridDim.y;
  const int wg = blockIdx.y * gx + blockIdx.x;
  const int cpx = nwg >> 3;
  const int swz = (wg & 7) * cpx + (wg >> 3);
  const int m0 = (swz / gx) * 256, n0 = (swz % gx) * 256;

  const bf16* Ab = A + zo.a[z];
  const bf16* Bb = B + zo.b[z];
  const long long coff = zo.c[z];
  const int wave = tid >> 6, lane = tid & 63;
  const int wm = wave >> 2, wn = wave & 3;         // 2 x 4 wave grid
  const int lr = lane & 15, lq = lane >> 4;
  const int swl = (lr >> 1) & 3;
  const int kcol = (lq ^ swl) << 3;                // swizzled k-slot (ushort idx)

  // staging: chunk c = tid + i*512, c in [0,1024): row=c>>2, dest slot=c&3,
  // source k-slot = (c&3) ^ ((row>>1)&3)  (XOR swizzle via pre-swizzled src)
  const int c0 = tid, c1 = tid + 512;
  const int row0 = c0 >> 2, sl0 = (c0 & 3) ^ ((row0 >> 1) & 3);
  const int row1 = c1 >> 2, sl1 = (c1 & 3) ^ ((row1 >> 1) & 3);
  const bf16* sA0 = Ab + (size_t)(m0 + row0) * lda + sl0 * 8;
  const bf16* sA1 = Ab + (size_t)(m0 + row1) * lda + sl1 * 8;
  const bf16* sB0 = Bb + (size_t)(n0 + row0) * ldb + sl0 * 8;
  const bf16* sB1 = Bb + (size_t)(n0 + row1) * ldb + sl1 * 8;
  const int dst0 = c0 * 8, dst1 = c1 * 8;          // LDS dest (ushort idx)

  const int nt = K >> 5;                           // K-tiles of 32

#define STAGE(ks_, D_)                                                         \
  do {                                                                         \
    gload16(sA0 + (ks_), (D_) + dst0);                                         \
    gload16(sA1 + (ks_), (D_) + dst1);                                         \
    gload16(sB0 + (ks_), (D_) + 8192 + dst0);                                  \
    gload16(sB1 + (ks_), (D_) + 8192 + dst1);                                  \
  } while (0)

#define RD_B(dst_, base_)                                                      \
  _Pragma("unroll")                                                            \
  for (int n_ = 0; n_ < 4; ++n_)                                               \
    dst_[n_] = *(const short8*)&(base_)[8192 + (wn * 64 + n_ * 16 + lr) * 32 + kcol];
#define RD_A0(dst_, base_)                                                     \
  _Pragma("unroll")                                                            \
  for (int m_ = 0; m_ < 4; ++m_)                                               \
    dst_[m_] = *(const short8*)&(base_)[(wm * 128 + m_ * 16 + lr) * 32 + kcol];
#define RD_A1(dst_, base_)                                                     \
  _Pragma("unroll")                                                            \
  for (int m_ = 0; m_ < 4; ++m_)                                               \
    dst_[m_] = *(const short8*)&(base_)[(wm * 128 + 64 + m_ * 16 + lr) * 32 + kcol];
#define MMH(mh_, A_, B_)                                                       \
  __builtin_amdgcn_s_setprio(1);                                               \
  _Pragma("unroll")                                                            \
  for (int m_ = 0; m_ < 4; ++m_)                                               \
    _Pragma("unroll")                                                          \
    for (int n_ = 0; n_ < 4; ++n_)                                             \
      acc[(mh_) * 4 + m_][n_] = __builtin_amdgcn_mfma_f32_16x16x32_bf16(       \
          A_[m_], B_[n_], acc[(mh_) * 4 + m_][n_], 0, 0, 0);                   \
  __builtin_amdgcn_s_setprio(0);

  // prologue: stage tiles 0,1,2; wait for tile 0; preload its fragments
  STAGE(0, smem);
  if (nt > 1) STAGE(32, smem + 16384);
  if (nt > 2) STAGE(64, smem + 32768);
  if (nt > 2)      asm volatile("s_waitcnt vmcnt(8)" ::: "memory");
  else if (nt > 1) asm volatile("s_waitcnt vmcnt(4)" ::: "memory");
  else             asm volatile("s_waitcnt vmcnt(0)" ::: "memory");
  __builtin_amdgcn_s_barrier();
  asm volatile("" ::: "memory");

  f32x4 acc[8][4] = {};
  short8 afA[4], afB[4], af1[4], bfA[4], bfB[4];
  RD_B(bfA, smem);
  RD_A0(afA, smem);

#define HALF(t_, AFC, BFC, AFN, BFN)                                           \
  do {                                                                         \
    if ((t_) >= nt - 2) asm volatile("s_waitcnt vmcnt(0)" ::: "memory");       \
    else                asm volatile("s_waitcnt vmcnt(4)" ::: "memory");       \
    __builtin_amdgcn_s_barrier();                                              \
    asm volatile("" ::: "memory");                                             \
    if ((t_) + 3 < nt) STAGE(((t_) + 3) * 32, smem + (((t_) + 3) & 3) * 16384);\
    const unsigned short* At_ = smem + ((t_) & 3) * 16384;                     \
    const unsigned short* An_ = smem + (((t_) + 1) & 3) * 16384;               \
    RD_A1(af1, At_);                                                           \
    __builtin_amdgcn_sched_barrier(0);                                         \
    MMH(0, AFC, BFC);                                                          \
    if ((t_) + 1 < nt) { RD_B(BFN, An_); RD_A0(AFN, An_); }                    \
    MMH(1, af1, BFC);                                                          \
  } while (0)

  for (int t = 0; t < nt; t += 2) {
    HALF(t, afA, bfA, afB, bfB);
    HALF(t + 1, afB, bfB, afA, bfA);
  }

#undef STAGE
#undef RD_B
#undef RD_A0
#undef RD_A1
#undef MMH
#undef HALF

  // epilogue: C/D layout col=lane&15, row=quad*4+reg
  const int colBase = n0 + wn * 64 + lr;
  float bv[4];
  #pragma unroll
  for (int n = 0; n < 4; ++n)
    bv[n] = (FLAGS & F_BIAS) ? bias[colBase + n * 16] : 0.0f;
  #pragma unroll
  for (int m = 0; m < 8; ++m) {
    #pragma unroll
    for (int n = 0; n < 4; ++n) {
      const int col = colBase + n * 16;
      #pragma unroll
      for (int r = 0; r < 4; ++r) {
        const int row = m0 + wm * 128 + m * 16 + lq * 4 + r;
        float v = acc[m][n][r];
        if (FLAGS & F_SCALE) v *= scale;
        v += bv[n];
        if (FLAGS & F_GELU) v = gelu_fast(v);
        if (FLAGS & F_RES) {
          size_t ridx = (size_t)row * ldc + col;
          v += (FLAGS & F_RESF32) ? ((const float*)res)[ridx]
                                  : bf2f(((const bf16*)res)[ridx]);
        }
        size_t idx = (size_t)coff + (size_t)row * ldc + col;
        if (FLAGS & F_OUTBF16) ((bf16*)Dst)[idx] = __float2bfloat16(v);
        else                   ((float*)Dst)[idx] = v;
      }
    }
  }
}

// ---------- weight transpose+convert: src fp32 [K,N] -> dst bf16 [N,K] ----------
__global__ __launch_bounds__(256) void tconv_kernel(
    const float* __restrict__ src, bf16* __restrict__ dst, int K, int N)
{
  __shared__ float t[32][33];
  int n0 = blockIdx.x * 32, k0 = blockIdx.y * 32;
  int c = threadIdx.x & 31, r = threadIdx.x >> 5;
  #pragma unroll
  for (int i = 0; i < 4; i++)
    t[r + i * 8][c] = src[(size_t)(k0 + r + i * 8) * N + n0 + c];
  __syncthreads();
  #pragma unroll
  for (int i = 0; i < 4; i++)
    dst[(size_t)(n0 + r + i * 8) * K + k0 + c] = __float2bfloat16(t[c][r + i * 8]);
}

// ---------- V transpose: qkv V-slice [n][d] -> Vt[bh][d][n] (bf16) ----------
__global__ __launch_bounds__(256) void vtrans_kernel(
    const bf16* __restrict__ qkv, bf16* __restrict__ vt)
{
  __shared__ unsigned short t[32][33];
  int bh = blockIdx.z, b = bh >> 1, h = bh & 1;
  int n0 = blockIdx.x * 32, d0 = blockIdx.y * 32;
  int c = threadIdx.x & 31, r = threadIdx.x >> 5;
  const bf16* src = qkv + (size_t)b * SEQ * H3 + 2 * C + (size_t)h * DH;
  #pragma unroll
  for (int i = 0; i < 4; i++)
    t[r + i * 8][c] = *(const unsigned short*)&src[(size_t)(n0 + r + i * 8) * H3 + d0 + c];
  __syncthreads();
  bf16* dst = vt + ((size_t)bh * DH + d0) * SEQ + n0;
  #pragma unroll
  for (int i = 0; i < 4; i++)
    *(unsigned short*)&dst[(size_t)(r + i * 8) * SEQ + c] = t[c][r + i * 8];
}

// ---------- vectorized loads for LN ----------
__device__ __forceinline__ void ld4(const float* p, float v[4]) {
  const float4 t = *(const float4*)p;
  v[0] = t.x; v[1] = t.y; v[2] = t.z; v[3] = t.w;
}
__device__ __forceinline__ void ld4(const bf16* p, float v[4]) {
  short4v t = *(const short4v*)p;
  #pragma unroll
  for (int i = 0; i < 4; ++i) v[i] = bf2f(((const bf16*)&t)[i]);
}

// ---------- LayerNorm over C=1024, one block per row (vectorized) ----------
template<typename T>
__global__ __launch_bounds__(256) void ln_kernel(
    const T* __restrict__ x,
    const float* __restrict__ w,
    const float* __restrict__ b,
    bf16* __restrict__ out)
{
  __shared__ float sm[4], sm2[4];
  int row = blockIdx.x, tid = threadIdx.x;
  float v[4];
  ld4(x + (size_t)row * 1024 + tid * 4, v);
  float s  = v[0] + v[1] + v[2] + v[3];
  float sq = v[0]*v[0] + v[1]*v[1] + v[2]*v[2] + v[3]*v[3];
  #pragma unroll
  for (int o = 32; o > 0; o >>= 1) {
    s  += __shfl_down(s, o, 64);
    sq += __shfl_down(sq, o, 64);
  }
  int wvi = tid >> 6, lnn = tid & 63;
  if (lnn == 0) { sm[wvi] = s; sm2[wvi] = sq; }
  __syncthreads();
  s  = sm[0] + sm[1] + sm[2] + sm[3];
  sq = sm2[0] + sm2[1] + sm2[2] + sm2[3];
  float mean = s * (1.0f / 1024.0f);
  float var  = sq * (1.0f / 1024.0f) - mean * mean;
  float rs = rsqrtf(var + 1e-5f);
  float wv4[4], bv4[4];
  ld4(w + tid * 4, wv4);
  ld4(b + tid * 4, bv4);
  short4v o4;
  #pragma unroll
  for (int i = 0; i < 4; ++i)
    ((bf16*)&o4)[i] = __float2bfloat16((v[i] - mean) * rs * wv4[i] + bv4[i]);
  *(short4v*)&out[(size_t)row * 1024 + tid * 4] = o4;
}

// ---------- row softmax over 2048, IN-PLACE (bf16, short8 vectorized) ----------
__global__ __launch_bounds__(256) void softmax_kernel(
    bf16* __restrict__ sc)
{
  __shared__ float sm[4];
  int tid = threadIdx.x;
  size_t base = ((size_t)blockIdx.y * 2048 + blockIdx.x) * 2048 + (size_t)tid * 8;
  short8 sv = *(const short8*)&sc[base];
  float v[8], m = -1e30f;
  #pragma unroll
  for (int i = 0; i < 8; i++) { v[i] = bf2f(((const bf16*)&sv)[i]); m = fmaxf(m, v[i]); }
  #pragma unroll
  for (int o = 32; o > 0; o >>= 1) m = fmaxf(m, __shfl_down(m, o, 64));
  int wvi = tid >> 6, lnn = tid & 63;
  if (lnn == 0) sm[wvi] = m;
  __syncthreads();
  m = fmaxf(fmaxf(sm[0], sm[1]), fmaxf(sm[2], sm[3]));
  __syncthreads();
  float s = 0.f;
  #pragma unroll
  for (int i = 0; i < 8; i++) { v[i] = __expf(v[i] - m); s += v[i]; }
  #pragma unroll
  for (int o = 32; o > 0; o >>= 1) s += __shfl_down(s, o, 64);
  if (lnn == 0) sm[wvi] = s;
  __syncthreads();
  s = sm[0] + sm[1] + sm[2] + sm[3];
  float inv = 1.0f / s;
  short8 ov;
  #pragma unroll
  for (int i = 0; i < 8; i++)
    ((bf16*)&ov)[i] = __float2bfloat16(v[i] * inv);
  *(short8*)&sc[base] = ov;
}

// ---------------- host ----------------
#define G256(FL, grid_, A_, B_, D_, bias_, res_, K_, lda_, ldb_, ldc_, sc_, zo_)      \
  do {                                                                                \
    (void)hipFuncSetAttribute(reinterpret_cast<const void*>(&gemm256_k<(FL)>),        \
                              hipFuncAttributeMaxDynamicSharedMemorySize, 131072);    \
    hipLaunchKernelGGL((gemm256_k<(FL)>), grid_, dim3(512), 131072, stream,           \
                       A_, B_, D_, bias_, res_, K_, lda_, ldb_, ldc_, sc_, zo_);      \
  } while (0)

extern "C" void kernel_launch(void* const* d_in, const int* in_sizes, int n_in,
                              void* d_out, int out_size, void* d_ws, size_t ws_size,
                              hipStream_t stream) {
  const float* x      = (const float*)d_in[0];
  const float* ln1_w  = (const float*)d_in[1];
  const float* ln1_b  = (const float*)d_in[2];
  const float* qkv_w  = (const float*)d_in[3];
  const float* qkv_b  = (const float*)d_in[4];
  const float* proj_w = (const float*)d_in[5];
  const float* proj_b = (const float*)d_in[6];
  const float* ln2_w  = (const float*)d_in[7];
  const float* ln2_b  = (const float*)d_in[8];
  const float* mlp_w1 = (const float*)d_in[9];
  const float* mlp_b1 = (const float*)d_in[10];
  const float* mlp_w2 = (const float*)d_in[11];
  const float* mlp_b2 = (const float*)d_in[12];
  float* out = (float*)d_out;

  char* ws = (char*)d_ws;
  const size_t MB = 1ull << 20;
  bf16* qkvT  = (bf16*)ws;
  bf16* projT = qkvT + 3 * 1024 * 1024;
  bf16* w1T   = qkvT + 4 * 1024 * 1024;
  bf16* w2T   = qkvT + 6 * 1024 * 1024;
  bf16* xn    = (bf16*)(ws + 16 * MB);
  bf16* qkvb  = (bf16*)(ws + 48 * MB);
  bf16* h1    = qkvb;
  bf16* Vt    = (bf16*)(ws + 144 * MB);

  int CH; bool useVt, x1f32;
  if      (ws_size >= 304 * MB) { CH = 16; useVt = true;  x1f32 = true;  }
  else if (ws_size >= 240 * MB) { CH = 8;  useVt = true;  x1f32 = true;  }
  else if (ws_size >= 208 * MB) { CH = 4;  useVt = true;  x1f32 = false; }
  else                          { CH = 4;  useVt = false; x1f32 = false; }
  char* R = ws + (useVt ? 176 * MB : 144 * MB);
  bf16*  scores = (bf16*)R;
  float* x1f    = (float*)R;   // overlays scores after attention
  bf16*  x1h    = (bf16*)R;

  ZOffs z0 = {};
  const float scale = 0.04419417382415922f;  // 1/sqrt(512)
  dim3 blk(256);

  // 0. weight transpose+convert
  hipLaunchKernelGGL(tconv_kernel, dim3(H3 / 32, C / 32), blk, 0, stream, qkv_w, qkvT, C, H3);
  hipLaunchKernelGGL(tconv_kernel, dim3(C / 32, C / 32), blk, 0, stream, proj_w, projT, C, C);
  hipLaunchKernelGGL(tconv_kernel, dim3(MH / 32, C / 32), blk, 0, stream, mlp_w1, w1T, C, MH);
  hipLaunchKernelGGL(tconv_kernel, dim3(C / 32, MH / 32), blk, 0, stream, mlp_w2, w2T, MH, C);

  // 1. LN1
  hipLaunchKernelGGL((ln_kernel<float>), dim3(MR), blk, 0, stream, x, ln1_w, ln1_b, xn);

  // 2. QKV = xn @ qkv_w + b -> bf16 [16384,3072]
  G256(F_TRANSB | F_BIAS | F_OUTBF16, dim3(H3 / 256, MR / 256, 1),
       xn, qkvT, (void*)qkvb, qkv_b, nullptr, C, C, C, H3, 1.0f, z0);

  // 2b. Vt
  if (useVt)
    hipLaunchKernelGGL(vtrans_kernel, dim3(SEQ / 32, DH / 32, 16), blk, 0, stream, qkvb, Vt);

  // 3. attention in chunks of CH (b,h) pairs
  for (int ch = 0; ch < 16 / CH; ch++) {
    ZOffs zq = {}, zp = {};
    for (int zz = 0; zz < CH; zz++) {
      int bh = ch * CH + zz, b = bh >> 1, hh = bh & 1;
      zq.a[zz] = (long long)b * SEQ * H3 + (long long)hh * DH;          // Q
      zq.b[zz] = (long long)b * SEQ * H3 + C + (long long)hh * DH;      // K
      zq.c[zz] = (long long)zz * SEQ * SEQ;                             // scores
      zp.a[zz] = (long long)zz * SEQ * SEQ;                             // probs
      zp.b[zz] = useVt ? (long long)bh * DH * SEQ                       // Vt slice
                       : (long long)b * SEQ * H3 + 2 * C + (long long)hh * DH;
      zp.c[zz] = (long long)b * SEQ * C + (long long)hh * DH;           // attn_out
    }
    G256(F_TRANSB | F_SCALE | F_OUTBF16, dim3(SEQ / 256, SEQ / 256, CH),
         qkvb, qkvb, (void*)scores, nullptr, nullptr, DH, H3, H3, SEQ, scale, zq);
    hipLaunchKernelGGL(softmax_kernel, dim3(SEQ, CH), blk, 0, stream, scores);
    if (useVt)
      G256(F_TRANSB | F_OUTBF16, dim3(DH / 256, SEQ / 256, CH),
           scores, Vt, (void*)xn, nullptr, nullptr, SEQ, SEQ, SEQ, C, 1.0f, zp);
    else
      hipLaunchKernelGGL((gemm_k<F_OUTBF16>),
                         dim3(DH / TILE, SEQ / TILE, CH), blk, 0, stream,
                         scores, qkvb, (void*)xn, nullptr, nullptr, SEQ, SEQ, H3, C, 1.0f, zp);
  }

  // 4. x1 = attn_out @ proj_w + b + x ; LN2 -> xn2
  if (x1f32) {
    G256(F_TRANSB | F_BIAS | F_RES | F_RESF32, dim3(C / 256, MR / 256, 1),
         xn, projT, (void*)x1f, proj_b, (const void*)x, C, C, C, C, 1.0f, z0);
    hipLaunchKernelGGL((ln_kernel<float>), dim3(MR), blk, 0, stream, x1f, ln2_w, ln2_b, xn);
  } else {
    G256(F_TRANSB | F_BIAS | F_RES | F_RESF32 | F_OUTBF16, dim3(C / 256, MR / 256, 1),
         xn, projT, (void*)x1h, proj_b, (const void*)x, C, C, C, C, 1.0f, z0);
    hipLaunchKernelGGL((ln_kernel<bf16>), dim3(MR), blk, 0, stream, x1h, ln2_w, ln2_b, xn);
  }

  // 5. h1 = gelu(xn2 @ w1 + b1) -> bf16 [16384,2048]
  G256(F_TRANSB | F_BIAS | F_GELU | F_OUTBF16, dim3(MH / 256, MR / 256, 1),
       xn, w1T, (void*)h1, mlp_b1, nullptr, C, C, C, MH, 1.0f, z0);

  // 6. out = x1 + h1 @ w2 + b2 -> fp32 d_out
  if (x1f32) {
    G256(F_TRANSB | F_BIAS | F_RES | F_RESF32, dim3(C / 256, MR / 256, 1),
         h1, w2T, (void*)out, mlp_b2, (const void*)x1f, MH, MH, MH, C, 1.0f, z0);
  } else {
    G256(F_TRANSB | F_BIAS | F_RES, dim3(C / 256, MR / 256, 1),
         h1, w2T, (void*)out, mlp_b2, (const void*)x1h, MH, MH, MH, C, 1.0f, z0);
  }
}

// Round 7
// 755.138 us; speedup vs baseline: 1.0619x; 1.0358x over previous
//
#include <hip/hip_runtime.h>
#include <hip/hip_bf16.h>
#include <math.h>

#define TILE 128
#define BK 32

using short8  = __attribute__((ext_vector_type(8))) short;
using short4v = __attribute__((ext_vector_type(4))) short;
using f32x4   = __attribute__((ext_vector_type(4))) float;
typedef __hip_bfloat16 bf16;

constexpr int BB = 8, SEQ = 2048, C = 1024, H3 = 3072, DH = 512, MH = 2048;
constexpr int MR = BB * SEQ;  // 16384 token rows

enum {
  F_TRANSB = 1,   // B given as [N,K] row-major
  F_GELU   = 2,
  F_RES    = 4,
  F_OUTBF16= 8,
  F_BIAS   = 16,
  F_SCALE  = 32,
  F_RESF32 = 64
};

struct ZOffs { long long a[16]; long long b[16]; long long c[16]; };

__device__ __forceinline__ float bf2f(bf16 h) { return __bfloat162float(h); }

// async global->LDS, 16B per lane; LDS dest is wave-uniform base + lane*16
__device__ __forceinline__ void gload16(const void* g, void* l) {
  __builtin_amdgcn_global_load_lds(
      (const __attribute__((address_space(1))) unsigned int*)g,
      (__attribute__((address_space(3))) unsigned int*)l, 16, 0, 0);
}

// fast GELU (tanh form): v - v/(e+1), e = exp(2*0.79788456*(v + 0.044715 v^3))
// max abs deviation from exact-erf GELU ~1e-3, below h1's bf16 quantization.
// Proven r5->r6: removed the 109us/VALU-43% erf MLP1 dispatch.
__device__ __forceinline__ float gelu_fast(float v) {
  float u2 = v * (1.5957691216057308f + 0.0713548162726009f * v * v);
  float e  = __expf(u2);
  return v - v * (1.0f / (e + 1.0f));
}

// ---------------------------------------------------------------------------
// OLD 128x128 GEMM (kept only for the no-Vt fallback PV path, B=[K,N] layout)
// ---------------------------------------------------------------------------
template<int FLAGS>
__global__ __launch_bounds__(256) void gemm_k(
    const bf16* __restrict__ A,
    const bf16* __restrict__ B,
    void* __restrict__ Dst,
    const float* __restrict__ bias,
    const void* __restrict__ res,
    int K, int lda, int ldb, int ldc,
    float scale, ZOffs zo)
{
  __shared__ __align__(16) unsigned short As[TILE * BK];
  __shared__ __align__(16) unsigned short Bs[TILE * BK];
  const int tid = threadIdx.x;
  const int z = blockIdx.z;
  const int m0 = blockIdx.y * TILE, n0 = blockIdx.x * TILE;
  const bf16* Ab = A + zo.a[z];
  const bf16* Bb = B + zo.b[z];
  const long long coff = zo.c[z];
  const int wave = tid >> 6, lane = tid & 63;
  const int wm = (wave & 1) << 6, wn = (wave >> 1) << 6;
  const int lr = lane & 15, lq = lane >> 4;

  int srow[2], skb[2];
  #pragma unroll
  for (int i = 0; i < 2; i++) {
    int c = tid + (i << 8);
    srow[i] = c >> 2;
    skb[i]  = (c & 3) ^ ((srow[i] >> 1) & 3);
  }
  const bf16* Asrc[2]; const bf16* Bsrc[2] = {nullptr, nullptr};
  #pragma unroll
  for (int i = 0; i < 2; i++)
    Asrc[i] = Ab + (size_t)(m0 + srow[i]) * lda + skb[i] * 8;
  if (FLAGS & F_TRANSB) {
    #pragma unroll
    for (int i = 0; i < 2; i++)
      Bsrc[i] = Bb + (size_t)(n0 + srow[i]) * ldb + skb[i] * 8;
  }

  f32x4 acc[4][4] = {};
  const int swl = (lr >> 1) & 3;

  for (int k0 = 0; k0 < K; k0 += BK) {
    #pragma unroll
    for (int i = 0; i < 2; i++)
      gload16(Asrc[i] + k0, &As[(tid + (i << 8)) * 8]);
    if (FLAGS & F_TRANSB) {
      #pragma unroll
      for (int i = 0; i < 2; i++)
        gload16(Bsrc[i] + k0, &Bs[(tid + (i << 8)) * 8]);
    } else {
      #pragma unroll
      for (int i = 0; i < 2; i++) {
        int c = tid + (i << 8);
        int kk = c >> 4, nn = (c & 15) << 3;
        unsigned short tmp[8];
        *(uint4*)tmp = *(const uint4*)(Bb + (size_t)(k0 + kk) * ldb + n0 + nn);
        #pragma unroll
        for (int j = 0; j < 8; j++) {
          int n = nn + j;
          Bs[n * BK + (((kk >> 3) ^ ((n >> 1) & 3)) << 3) + (kk & 7)] = tmp[j];
        }
      }
    }
    __syncthreads();
    short8 af[4], bfr[4];
    #pragma unroll
    for (int mi = 0; mi < 4; mi++)
      af[mi] = *(const short8*)&As[(wm + mi * 16 + lr) * BK + ((lq ^ swl) << 3)];
    #pragma unroll
    for (int ni = 0; ni < 4; ni++)
      bfr[ni] = *(const short8*)&Bs[(wn + ni * 16 + lr) * BK + ((lq ^ swl) << 3)];
    #pragma unroll
    for (int mi = 0; mi < 4; mi++)
      #pragma unroll
      for (int ni = 0; ni < 4; ni++)
        acc[mi][ni] = __builtin_amdgcn_mfma_f32_16x16x32_bf16(
            af[mi], bfr[ni], acc[mi][ni], 0, 0, 0);
    __syncthreads();
  }

  #pragma unroll
  for (int mi = 0; mi < 4; mi++) {
    #pragma unroll
    for (int ni = 0; ni < 4; ni++) {
      int col = n0 + wn + ni * 16 + lr;
      float bv = (FLAGS & F_BIAS) ? bias[col] : 0.0f;
      #pragma unroll
      for (int r = 0; r < 4; r++) {
        int row = m0 + wm + mi * 16 + lq * 4 + r;
        float v = acc[mi][ni][r];
        if (FLAGS & F_SCALE) v *= scale;
        v += bv;
        if (FLAGS & F_GELU) v = gelu_fast(v);
        if (FLAGS & F_RES) {
          size_t ridx = (size_t)row * ldc + col;
          v += (FLAGS & F_RESF32) ? ((const float*)res)[ridx]
                                  : bf2f(((const bf16*)res)[ridx]);
        }
        size_t idx = (size_t)coff + (size_t)row * ldc + col;
        if (FLAGS & F_OUTBF16) ((bf16*)Dst)[idx] = __float2bfloat16(v);
        else                   ((float*)Dst)[idx] = v;
      }
    }
  }
}

// ---------------------------------------------------------------------------
// 256x256 GEMM, BK=64, 512 threads = 8 waves (2M x 4N), per-wave 128x64 out.
// r2 structure (best whole-run: 765us) + sched_barrier(0) pins.
// WHY THE PINS: __builtin_amdgcn_s_barrier is IntrNoMem in LLVM, so the
// scheduler may legally sink LDS reads past it (and MFMAs are register-only,
// so asm "memory" clobbers don't order them either - guide rule #18). Four
// schedule variants all measured identically (~38% MfmaUtil) because the
// emitted order likely re-converged to [all reads; wait; all MFMA] convoy.
// sched_barrier(0) at each cluster boundary pins the intended order:
//   [reads issue] |pin| [s_barrier: reads execute under rendezvous] |pin|
//   [16-MFMA cluster].
// B fragments register-cached across phases (bk0 live P0->P3, bk1 P1->P2).
// Staging of tile t+2 split 2+6 at P0/P2 into dead LDS regions; steady-state
// counted s_waitcnt vmcnt(6) at tile top (never 0 until the last tile).
// T1 XCD swizzle, T2 XOR slot swizzle (0 bank conflicts), T5 setprio.
// Requires F_TRANSB, M,N % 256 == 0, K % 128 == 0 (nt >= 2).
// ---------------------------------------------------------------------------
template<int FLAGS>
__global__ __launch_bounds__(512, 2) void gemm256_k(
    const bf16* __restrict__ A,
    const bf16* __restrict__ B,
    void* __restrict__ Dst,
    const float* __restrict__ bias,
    const void* __restrict__ res,
    int K, int lda, int ldb, int ldc,
    float scale, ZOffs zo)
{
  static_assert(FLAGS & F_TRANSB, "gemm256_k requires B^T layout");
  extern __shared__ __align__(16) unsigned short smem[];  // [A0|A1|B0|B1] 4x32KB

  const int tid = threadIdx.x;
  const int z = blockIdx.z;

  // T1: bijective XCD swizzle over (bx,by); all grids have nwg % 8 == 0.
  const int gx = gridDim.x;
  const int nwg = gx * gridDim.y;
  const int wg = blockIdx.y * gx + blockIdx.x;
  const int cpx = nwg >> 3;
  const int swz = (wg & 7) * cpx + (wg >> 3);
  const int m0 = (swz / gx) * 256, n0 = (swz % gx) * 256;

  const bf16* Ab = A + zo.a[z];
  const bf16* Bb = B + zo.b[z];
  const long long coff = zo.c[z];
  const int wave = tid >> 6, lane = tid & 63;
  const int wm = wave >> 2, wn = wave & 3;         // 2 x 4 wave grid
  const int lr = lane & 15, lq = lane >> 4;
  const int r7 = lr & 7;
  const int sk0 = (lq ^ r7) << 3;                  // k-half 0 slot (ushort idx)
  const int sk1 = ((4 + lq) ^ r7) << 3;            // k-half 1 slot
  const int rowA = (wm * 128 + lr) * 64;           // base in A buf (ushorts)
  const int rowB = (wn * 64 + lr) * 64;            // base in B buf

  // staging geometry: 8 gloads/thread per K-tile (A: 4, B: 4)
  const int t8 = tid >> 3, s8 = tid & 7;
  const int sslot = (s8 ^ (t8 & 7)) << 3;          // pre-swizzled source k-slot
  const bf16* srcA = Ab + (size_t)(m0 + t8) * lda + sslot;
  const int rB0 = (t8 & 31) + ((t8 >> 5) << 6);
  const bf16* srcB = Bb + (size_t)(n0 + rB0) * ldb + sslot;
  const int dA0 = tid * 8;                         // LDS dest (ushort idx)
  const int dB0 = rB0 * 64 + s8 * 8;

  const int nt = K >> 6;                           // K-tiles of 64

#define SA(h_, ks_, Ad_)                                                       \
  do {                                                                         \
    gload16(srcA + (size_t)((h_) * 64) * lda + (ks_),                          \
            (Ad_) + dA0 + (h_) * 4096);                                        \
    gload16(srcA + (size_t)((h_) * 64 + 128) * lda + (ks_),                    \
            (Ad_) + dA0 + (h_) * 4096 + 8192);                                 \
  } while (0)
#define SB(h_, ks_, Bd_)                                                       \
  do {                                                                         \
    gload16(srcB + (size_t)((h_) * 32) * ldb + (ks_),                          \
            (Bd_) + dB0 + (h_) * 2048);                                        \
    gload16(srcB + (size_t)((h_) * 32 + 128) * ldb + (ks_),                    \
            (Bd_) + dB0 + (h_) * 2048 + 8192);                                 \
  } while (0)
#define SCHED0() __builtin_amdgcn_sched_barrier(0)

  // prologue: fully stage tiles 0 and 1 (8 gloads each, FIFO order)
  {
    const int npro = nt < 2 ? nt : 2;
    for (int t = 0; t < npro; ++t) {
      unsigned short* Ad = smem + (t & 1) * 16384;
      unsigned short* Bd = smem + 32768 + (t & 1) * 16384;
      const int ks = t * 64;
      SA(0, ks, Ad); SA(1, ks, Ad); SB(0, ks, Bd); SB(1, ks, Bd);
    }
  }

  f32x4 acc[8][4] = {};
  short8 af[4], bk0[4], bk1[4];

#define RD_AF(mh_, sk_)                                                        \
  _Pragma("unroll")                                                            \
  for (int m_ = 0; m_ < 4; ++m_)                                               \
    af[m_] = *(const short8*)&At[rowA + ((mh_) * 64 + m_ * 16) * 64 + (sk_)];
#define RD_BF(b_, sk_)                                                         \
  _Pragma("unroll")                                                            \
  for (int n_ = 0; n_ < 4; ++n_)                                               \
    b_[n_] = *(const short8*)&Bt[rowB + (n_ * 16) * 64 + (sk_)];
#define MM16(mh_, b_)                                                          \
  __builtin_amdgcn_s_setprio(1);                                               \
  _Pragma("unroll")                                                            \
  for (int m_ = 0; m_ < 4; ++m_)                                               \
    _Pragma("unroll")                                                          \
    for (int n_ = 0; n_ < 4; ++n_)                                             \
      acc[(mh_) * 4 + m_][n_] =                                                \
          __builtin_amdgcn_mfma_f32_16x16x32_bf16(                             \
              af[m_], b_[n_], acc[(mh_) * 4 + m_][n_], 0, 0, 0);               \
  __builtin_amdgcn_s_setprio(0);

  for (int t = 0; t < nt; ++t) {
    // Tile-boundary counted wait (T4). FIFO accounting:
    //  t==0: tiles 0+1 staged in prologue -> keep tile 1's 8 in flight.
    //  steady: keep tile (t+1)'s partial 6 (SA0+SB issued at P2 of t-1);
    //          tile t's SA1 (issued P0 of t-1) and older are retired.
    //  t==nt-1: nothing newer in flight -> drain.
    if (t == 0)           asm volatile("s_waitcnt vmcnt(8)" ::: "memory");
    else if (t == nt - 1) asm volatile("s_waitcnt vmcnt(0)" ::: "memory");
    else                  asm volatile("s_waitcnt vmcnt(6)" ::: "memory");
    __builtin_amdgcn_s_barrier();

    const unsigned short* At = smem + (t & 1) * 16384;
    const unsigned short* Bt = smem + 32768 + (t & 1) * 16384;

    // P0 (mh0, k0): 8 ds_reads; stage SA1 for tile t+1 into buf[(t+1)&1]
    RD_AF(0, sk0);
    RD_BF(bk0, sk0);
    if (t > 0 && t + 1 < nt) {
      unsigned short* Ad = smem + ((t + 1) & 1) * 16384;
      SA(1, (t + 1) * 64, Ad);
    }
    SCHED0();
    __builtin_amdgcn_s_barrier();
    SCHED0();
    MM16(0, bk0);
    SCHED0();
    __builtin_amdgcn_s_barrier();

    // P1 (mh0, k1): 8 ds_reads
    RD_AF(0, sk1);
    RD_BF(bk1, sk1);
    SCHED0();
    __builtin_amdgcn_s_barrier();
    SCHED0();
    MM16(0, bk1);
    SCHED0();
    __builtin_amdgcn_s_barrier();

    // P2 (mh1, k1): 4 ds_reads; stage SA0+SB for tile t+2 into buf[t&1]
    RD_AF(1, sk1);
    if (t + 2 < nt) {
      unsigned short* Ad = smem + (t & 1) * 16384;
      unsigned short* Bd = smem + 32768 + (t & 1) * 16384;
      const int ks = (t + 2) * 64;
      SA(0, ks, Ad); SB(0, ks, Bd); SB(1, ks, Bd);
    }
    SCHED0();
    __builtin_amdgcn_s_barrier();
    SCHED0();
    MM16(1, bk1);
    SCHED0();
    __builtin_amdgcn_s_barrier();

    // P3 (mh1, k0): 4 ds_reads (bk0 still live in regs)
    RD_AF(1, sk0);
    SCHED0();
    __builtin_amdgcn_s_barrier();
    SCHED0();
    MM16(1, bk0);
    SCHED0();
    // tile-boundary barrier comes from loop top (after counted vmcnt)
  }

#undef SA
#undef SB
#undef SCHED0
#undef RD_AF
#undef RD_BF
#undef MM16

  // epilogue: C/D layout col=lane&15, row=quad*4+reg
  const int colBase = n0 + wn * 64 + lr;
  float bv[4];
  #pragma unroll
  for (int n = 0; n < 4; ++n)
    bv[n] = (FLAGS & F_BIAS) ? bias[colBase + n * 16] : 0.0f;
  #pragma unroll
  for (int m = 0; m < 8; ++m) {
    #pragma unroll
    for (int n = 0; n < 4; ++n) {
      const int col = colBase + n * 16;
      #pragma unroll
      for (int r = 0; r < 4; ++r) {
        const int row = m0 + wm * 128 + m * 16 + lq * 4 + r;
        float v = acc[m][n][r];
        if (FLAGS & F_SCALE) v *= scale;
        v += bv[n];
        if (FLAGS & F_GELU) v = gelu_fast(v);
        if (FLAGS & F_RES) {
          size_t ridx = (size_t)row * ldc + col;
          v += (FLAGS & F_RESF32) ? ((const float*)res)[ridx]
                                  : bf2f(((const bf16*)res)[ridx]);
        }
        size_t idx = (size_t)coff + (size_t)row * ldc + col;
        if (FLAGS & F_OUTBF16) ((bf16*)Dst)[idx] = __float2bfloat16(v);
        else                   ((float*)Dst)[idx] = v;
      }
    }
  }
}

// ---------- weight transpose+convert: src fp32 [K,N] -> dst bf16 [N,K] ----------
__global__ __launch_bounds__(256) void tconv_kernel(
    const float* __restrict__ src, bf16* __restrict__ dst, int K, int N)
{
  __shared__ float t[32][33];
  int n0 = blockIdx.x * 32, k0 = blockIdx.y * 32;
  int c = threadIdx.x & 31, r = threadIdx.x >> 5;
  #pragma unroll
  for (int i = 0; i < 4; i++)
    t[r + i * 8][c] = src[(size_t)(k0 + r + i * 8) * N + n0 + c];
  __syncthreads();
  #pragma unroll
  for (int i = 0; i < 4; i++)
    dst[(size_t)(n0 + r + i * 8) * K + k0 + c] = __float2bfloat16(t[c][r + i * 8]);
}

// ---------- V transpose: qkv V-slice [n][d] -> Vt[bh][d][n] (bf16) ----------
__global__ __launch_bounds__(256) void vtrans_kernel(
    const bf16* __restrict__ qkv, bf16* __restrict__ vt)
{
  __shared__ unsigned short t[32][33];
  int bh = blockIdx.z, b = bh >> 1, h = bh & 1;
  int n0 = blockIdx.x * 32, d0 = blockIdx.y * 32;
  int c = threadIdx.x & 31, r = threadIdx.x >> 5;
  const bf16* src = qkv + (size_t)b * SEQ * H3 + 2 * C + (size_t)h * DH;
  #pragma unroll
  for (int i = 0; i < 4; i++)
    t[r + i * 8][c] = *(const unsigned short*)&src[(size_t)(n0 + r + i * 8) * H3 + d0 + c];
  __syncthreads();
  bf16* dst = vt + ((size_t)bh * DH + d0) * SEQ + n0;
  #pragma unroll
  for (int i = 0; i < 4; i++)
    *(unsigned short*)&dst[(size_t)(r + i * 8) * SEQ + c] = t[c][r + i * 8];
}

// ---------- vectorized loads for LN ----------
__device__ __forceinline__ void ld4(const float* p, float v[4]) {
  const float4 t = *(const float4*)p;
  v[0] = t.x; v[1] = t.y; v[2] = t.z; v[3] = t.w;
}
__device__ __forceinline__ void ld4(const bf16* p, float v[4]) {
  short4v t = *(const short4v*)p;
  #pragma unroll
  for (int i = 0; i < 4; ++i) v[i] = bf2f(((const bf16*)&t)[i]);
}

// ---------- LayerNorm over C=1024, one block per row (vectorized) ----------
template<typename T>
__global__ __launch_bounds__(256) void ln_kernel(
    const T* __restrict__ x,
    const float* __restrict__ w,
    const float* __restrict__ b,
    bf16* __restrict__ out)
{
  __shared__ float sm[4], sm2[4];
  int row = blockIdx.x, tid = threadIdx.x;
  float v[4];
  ld4(x + (size_t)row * 1024 + tid * 4, v);
  float s  = v[0] + v[1] + v[2] + v[3];
  float sq = v[0]*v[0] + v[1]*v[1] + v[2]*v[2] + v[3]*v[3];
  #pragma unroll
  for (int o = 32; o > 0; o >>= 1) {
    s  += __shfl_down(s, o, 64);
    sq += __shfl_down(sq, o, 64);
  }
  int wvi = tid >> 6, lnn = tid & 63;
  if (lnn == 0) { sm[wvi] = s; sm2[wvi] = sq; }
  __syncthreads();
  s  = sm[0] + sm[1] + sm[2] + sm[3];
  sq = sm2[0] + sm2[1] + sm2[2] + sm2[3];
  float mean = s * (1.0f / 1024.0f);
  float var  = sq * (1.0f / 1024.0f) - mean * mean;
  float rs = rsqrtf(var + 1e-5f);
  float wv4[4], bv4[4];
  ld4(w + tid * 4, wv4);
  ld4(b + tid * 4, bv4);
  short4v o4;
  #pragma unroll
  for (int i = 0; i < 4; ++i)
    ((bf16*)&o4)[i] = __float2bfloat16((v[i] - mean) * rs * wv4[i] + bv4[i]);
  *(short4v*)&out[(size_t)row * 1024 + tid * 4] = o4;
}

// ---------- row softmax over 2048, IN-PLACE (bf16, short8 vectorized) ----------
__global__ __launch_bounds__(256) void softmax_kernel(
    bf16* __restrict__ sc)
{
  __shared__ float sm[4];
  int tid = threadIdx.x;
  size_t base = ((size_t)blockIdx.y * 2048 + blockIdx.x) * 2048 + (size_t)tid * 8;
  short8 sv = *(const short8*)&sc[base];
  float v[8], m = -1e30f;
  #pragma unroll
  for (int i = 0; i < 8; i++) { v[i] = bf2f(((const bf16*)&sv)[i]); m = fmaxf(m, v[i]); }
  #pragma unroll
  for (int o = 32; o > 0; o >>= 1) m = fmaxf(m, __shfl_down(m, o, 64));
  int wvi = tid >> 6, lnn = tid & 63;
  if (lnn == 0) sm[wvi] = m;
  __syncthreads();
  m = fmaxf(fmaxf(sm[0], sm[1]), fmaxf(sm[2], sm[3]));
  __syncthreads();
  float s = 0.f;
  #pragma unroll
  for (int i = 0; i < 8; i++) { v[i] = __expf(v[i] - m); s += v[i]; }
  #pragma unroll
  for (int o = 32; o > 0; o >>= 1) s += __shfl_down(s, o, 64);
  if (lnn == 0) sm[wvi] = s;
  __syncthreads();
  s = sm[0] + sm[1] + sm[2] + sm[3];
  float inv = 1.0f / s;
  short8 ov;
  #pragma unroll
  for (int i = 0; i < 8; i++)
    ((bf16*)&ov)[i] = __float2bfloat16(v[i] * inv);
  *(short8*)&sc[base] = ov;
}

// ---------------- host ----------------
#define G256(FL, grid_, A_, B_, D_, bias_, res_, K_, lda_, ldb_, ldc_, sc_, zo_)      \
  do {                                                                                \
    (void)hipFuncSetAttribute(reinterpret_cast<const void*>(&gemm256_k<(FL)>),        \
                              hipFuncAttributeMaxDynamicSharedMemorySize, 131072);    \
    hipLaunchKernelGGL((gemm256_k<(FL)>), grid_, dim3(512), 131072, stream,           \
                       A_, B_, D_, bias_, res_, K_, lda_, ldb_, ldc_, sc_, zo_);      \
  } while (0)

extern "C" void kernel_launch(void* const* d_in, const int* in_sizes, int n_in,
                              void* d_out, int out_size, void* d_ws, size_t ws_size,
                              hipStream_t stream) {
  const float* x      = (const float*)d_in[0];
  const float* ln1_w  = (const float*)d_in[1];
  const float* ln1_b  = (const float*)d_in[2];
  const float* qkv_w  = (const float*)d_in[3];
  const float* qkv_b  = (const float*)d_in[4];
  const float* proj_w = (const float*)d_in[5];
  const float* proj_b = (const float*)d_in[6];
  const float* ln2_w  = (const float*)d_in[7];
  const float* ln2_b  = (const float*)d_in[8];
  const float* mlp_w1 = (const float*)d_in[9];
  const float* mlp_b1 = (const float*)d_in[10];
  const float* mlp_w2 = (const float*)d_in[11];
  const float* mlp_b2 = (const float*)d_in[12];
  float* out = (float*)d_out;

  char* ws = (char*)d_ws;
  const size_t MB = 1ull << 20;
  bf16* qkvT  = (bf16*)ws;
  bf16* projT = qkvT + 3 * 1024 * 1024;
  bf16* w1T   = qkvT + 4 * 1024 * 1024;
  bf16* w2T   = qkvT + 6 * 1024 * 1024;
  bf16* xn    = (bf16*)(ws + 16 * MB);
  bf16* qkvb  = (bf16*)(ws + 48 * MB);
  bf16* h1    = qkvb;
  bf16* Vt    = (bf16*)(ws + 144 * MB);

  int CH; bool useVt, x1f32;
  if      (ws_size >= 304 * MB) { CH = 16; useVt = true;  x1f32 = true;  }
  else if (ws_size >= 240 * MB) { CH = 8;  useVt = true;  x1f32 = true;  }
  else if (ws_size >= 208 * MB) { CH = 4;  useVt = true;  x1f32 = false; }
  else                          { CH = 4;  useVt = false; x1f32 = false; }
  char* R = ws + (useVt ? 176 * MB : 144 * MB);
  bf16*  scores = (bf16*)R;
  float* x1f    = (float*)R;   // overlays scores after attention
  bf16*  x1h    = (bf16*)R;

  ZOffs z0 = {};
  const float scale = 0.04419417382415922f;  // 1/sqrt(512)
  dim3 blk(256);

  // 0. weight transpose+convert
  hipLaunchKernelGGL(tconv_kernel, dim3(H3 / 32, C / 32), blk, 0, stream, qkv_w, qkvT, C, H3);
  hipLaunchKernelGGL(tconv_kernel, dim3(C / 32, C / 32), blk, 0, stream, proj_w, projT, C, C);
  hipLaunchKernelGGL(tconv_kernel, dim3(MH / 32, C / 32), blk, 0, stream, mlp_w1, w1T, C, MH);
  hipLaunchKernelGGL(tconv_kernel, dim3(C / 32, MH / 32), blk, 0, stream, mlp_w2, w2T, MH, C);

  // 1. LN1
  hipLaunchKernelGGL((ln_kernel<float>), dim3(MR), blk, 0, stream, x, ln1_w, ln1_b, xn);

  // 2. QKV = xn @ qkv_w + b -> bf16 [16384,3072]
  G256(F_TRANSB | F_BIAS | F_OUTBF16, dim3(H3 / 256, MR / 256, 1),
       xn, qkvT, (void*)qkvb, qkv_b, nullptr, C, C, C, H3, 1.0f, z0);

  // 2b. Vt
  if (useVt)
    hipLaunchKernelGGL(vtrans_kernel, dim3(SEQ / 32, DH / 32, 16), blk, 0, stream, qkvb, Vt);

  // 3. attention in chunks of CH (b,h) pairs
  for (int ch = 0; ch < 16 / CH; ch++) {
    ZOffs zq = {}, zp = {};
    for (int zz = 0; zz < CH; zz++) {
      int bh = ch * CH + zz, b = bh >> 1, hh = bh & 1;
      zq.a[zz] = (long long)b * SEQ * H3 + (long long)hh * DH;          // Q
      zq.b[zz] = (long long)b * SEQ * H3 + C + (long long)hh * DH;      // K
      zq.c[zz] = (long long)zz * SEQ * SEQ;                             // scores
      zp.a[zz] = (long long)zz * SEQ * SEQ;                             // probs
      zp.b[zz] = useVt ? (long long)bh * DH * SEQ                       // Vt slice
                       : (long long)b * SEQ * H3 + 2 * C + (long long)hh * DH;
      zp.c[zz] = (long long)b * SEQ * C + (long long)hh * DH;           // attn_out
    }
    G256(F_TRANSB | F_SCALE | F_OUTBF16, dim3(SEQ / 256, SEQ / 256, CH),
         qkvb, qkvb, (void*)scores, nullptr, nullptr, DH, H3, H3, SEQ, scale, zq);
    hipLaunchKernelGGL(softmax_kernel, dim3(SEQ, CH), blk, 0, stream, scores);
    if (useVt)
      G256(F_TRANSB | F_OUTBF16, dim3(DH / 256, SEQ / 256, CH),
           scores, Vt, (void*)xn, nullptr, nullptr, SEQ, SEQ, SEQ, C, 1.0f, zp);
    else
      hipLaunchKernelGGL((gemm_k<F_OUTBF16>),
                         dim3(DH / TILE, SEQ / TILE, CH), blk, 0, stream,
                         scores, qkvb, (void*)xn, nullptr, nullptr, SEQ, SEQ, H3, C, 1.0f, zp);
  }

  // 4. x1 = attn_out @ proj_w + b + x ; LN2 -> xn2
  if (x1f32) {
    G256(F_TRANSB | F_BIAS | F_RES | F_RESF32, dim3(C / 256, MR / 256, 1),
         xn, projT, (void*)x1f, proj_b, (const void*)x, C, C, C, C, 1.0f, z0);
    hipLaunchKernelGGL((ln_kernel<float>), dim3(MR), blk, 0, stream, x1f, ln2_w, ln2_b, xn);
  } else {
    G256(F_TRANSB | F_BIAS | F_RES | F_RESF32 | F_OUTBF16, dim3(C / 256, MR / 256, 1),
         xn, projT, (void*)x1h, proj_b, (const void*)x, C, C, C, C, 1.0f, z0);
    hipLaunchKernelGGL((ln_kernel<bf16>), dim3(MR), blk, 0, stream, x1h, ln2_w, ln2_b, xn);
  }

  // 5. h1 = gelu(xn2 @ w1 + b1) -> bf16 [16384,2048]
  G256(F_TRANSB | F_BIAS | F_GELU | F_OUTBF16, dim3(MH / 256, MR / 256, 1),
       xn, w1T, (void*)h1, mlp_b1, nullptr, C, C, C, MH, 1.0f, z0);

  // 6. out = x1 + h1 @ w2 + b2 -> fp32 d_out
  if (x1f32) {
    G256(F_TRANSB | F_BIAS | F_RES | F_RESF32, dim3(C / 256, MR / 256, 1),
         h1, w2T, (void*)out, mlp_b2, (const void*)x1f, MH, MH, MH, C, 1.0f, z0);
  } else {
    G256(F_TRANSB | F_BIAS | F_RES, dim3(C / 256, MR / 256, 1),
         h1, w2T, (void*)out, mlp_b2, (const void*)x1h, MH, MH, MH, C, 1.0f, z0);
  }
}